// Round 8
// baseline (208.275 us; speedup 1.0000x reference)
//
#include <hip/hip_runtime.h>
#include <stdint.h>

typedef unsigned int uint32;
typedef int v4i __attribute__((ext_vector_type(4)));

#define BB 64
#define CC 256
#define OO 256
#define HH 28
#define WW 28
#define HWP 784           // 28*28
#define NWT 589824        // 256*256*9

// ===========================================================================
// ============================ MFMA i8 PATH =================================
// ===========================================================================

// ---------------------------------------------------------------------------
// pack_a8: x (f32 NCHW) -> a8[b][p][c] i8 in {+1,-1}.  LDS transpose so both
// the strided x reads (lanes = consecutive p) and the global writes (256B
// c-rows) are coalesced; LDS padded to 65 words -> conflict-free.
// ---------------------------------------------------------------------------
__global__ __launch_bounds__(256) void pack_a8_kernel(
    const float* __restrict__ x, char* __restrict__ a8) {
  __shared__ uint32 tt[56 * 65];
  const int pg = blockIdx.x;  // 0..13 (56 px each)
  const int b = blockIdx.y;
  const int tid = threadIdx.x;
  const int p0 = pg * 56;
  if (tid < 224) {
    int px = tid % 56, g = tid / 56;  // g: 0..3 covers c4 groups of 16
    const float* xb = x + (size_t)b * CC * HWP + p0 + px;
#pragma unroll
    for (int ii = 0; ii < 16; ++ii) {
      int c4 = g * 16 + ii;
      uint32 wd = 0;
#pragma unroll
      for (int i = 0; i < 4; ++i) {
        float v = xb[(size_t)(c4 * 4 + i) * HWP];
        wd |= ((v > 0.0f) ? 0x01u : 0xFFu) << (8 * i);
      }
      tt[px * 65 + c4] = wd;
    }
  }
  __syncthreads();
  for (int j = tid; j < 56 * 64; j += 256) {
    int px = j >> 6, c4 = j & 63;
    ((uint32*)a8)[(((size_t)b * HWP + p0 + px) << 6) + c4] = tt[px * 65 + c4];
  }
}

// ---------------------------------------------------------------------------
// pack_w8: w8t[o][tap*256 + c] i8 in {+1,-1}, k-major per o for MFMA A-frags.
// sign(w) = sign(M + rv.z) (positive rsqrt normalizer). Coalesced staged
// reads as in the verified pack_w; tiny scattered byte writes at the end.
// ---------------------------------------------------------------------------
__global__ __launch_bounds__(256) void pack_w8_kernel(
    const float* __restrict__ M, const float* __restrict__ Z,
    const float* __restrict__ rv, char* __restrict__ w8t) {
  __shared__ float sacc[576];
  const int o = blockIdx.x;   // 0..255
  const int jh = blockIdx.y;  // 0..3 (c blocks of 64)
  const int tid = threadIdx.x;
  const size_t base = (size_t)o * 2304 + (size_t)jh * 576;

  float r[8];
#pragma unroll
  for (int k = 0; k < 8; ++k) r[k] = rv[k];

#pragma unroll
  for (int ii = 0; ii < 3; ++ii) {
    int i = tid + ii * 256;
    if (i < 576) {
      float s = M[base + i];
#pragma unroll
      for (int k = 0; k < 8; ++k) s += r[k] * Z[(size_t)k * NWT + base + i];
      sacc[i] = s;  // local n-index: i = c_local*9 + tap
    }
  }
  __syncthreads();

  for (int t = tid; t < 576; t += 256) {
    int tap = t % 9, cl = t / 9;
    w8t[(size_t)o * 2304 + tap * 256 + jh * 64 + cl] =
        (sacc[cl * 9 + tap] > 0.0f) ? (char)1 : (char)-1;
  }
}

// ---------------------------------------------------------------------------
// conv_mfma: implicit-GEMM binary conv on the i8 matrix cores.
//   D[m=o][n=px] += A[m][k=c] * B[k=c][n=px(tap-shift)] per tap, K=256/tap.
// Block = (64-px tile, b); LDS holds the zero-padded activation slab
// At[ppad=lrow*30+col][c] (272B stride: 68 words, 2-way banks = free).
// 4 waves = 4 o-groups of 64; wave = 4 m-tiles x 4 n-tiles so one
// ds_read_b128 B-frag feeds 4 MFMAs (LDS 12cyc < 4x5.1cyc MFMA).
// Frag layouts: A/B lane-symmetric (m-or-n = lane&15, k = quad*16+j);
// C/D col=lane&15=n, row=quad*4+reg=m (HW-verified, dtype-independent).
// Zero padding is exact i8 zeros -> no border correction needed.
// ---------------------------------------------------------------------------
#define CBYTES 272
#define TROWS 6
#define PPMAX (TROWS * 30)  // 180

__global__ __launch_bounds__(256, 4) void conv_mfma(
    const char* __restrict__ a8, const char* __restrict__ w8t,
    const float* __restrict__ alpha, float* __restrict__ out) {
  __shared__ char At[PPMAX * CBYTES];  // 48,960 B
  const int pxg = blockIdx.x;          // 0..12 (64 px each; last ragged)
  const int b = blockIdx.y;
  const int tid = threadIdx.x;
  const int p0 = pxg * 64;
  const int h0 = p0 / WW;

  // Zero the slab (borders / out-of-image stay 0).
  for (int i = tid; i < (PPMAX * CBYTES) / 16; i += 256)
    ((uint4*)At)[i] = make_uint4(0, 0, 0, 0);
  __syncthreads();

  // Fill rows h0-1 .. h0+4 (center rows span <= h0+3, +1 halo).
  for (int lr = 0; lr < TROWS; ++lr) {
    int r = h0 - 1 + lr;
    if (r < 0 || r >= HH) continue;
    for (int idx = tid; idx < 448; idx += 256) {  // 28 w x 16 x 16B
      int w = idx >> 4, i16 = idx & 15;
      uint4 v = *(const uint4*)(a8 +
                 (((size_t)(b * HWP + r * WW + w)) << 8) + i16 * 16);
      *(uint4*)(At + (lr * 30 + w + 1) * CBYTES + i16 * 16) = v;
    }
  }
  __syncthreads();

  const int lane = tid & 63, q = lane >> 4, n15 = lane & 15;
  const int ob = (tid >> 6) * 64;  // wave = o-group of 64

  int av[4];   // LDS base addr per n-tile (biased by -31 rows for taps)
  int wva[4];  // per-lane weight byte offset per m-tile
#pragma unroll
  for (int nt = 0; nt < 4; ++nt) {
    int p = p0 + nt * 16 + n15;
    if (p > HWP - 1) p = HWP - 1;  // ragged tail: compute-dup, store-skip
    int h = p / WW, w = p - h * WW;
    av[nt] = ((h - h0 + 1) * 30 + w + 1 - 31) * CBYTES + q * 16;
  }
#pragma unroll
  for (int mi = 0; mi < 4; ++mi)
    wva[mi] = (ob + mi * 16 + n15) * 2304 + q * 16;

  v4i acc[4][4];
#pragma unroll
  for (int i = 0; i < 4; ++i)
#pragma unroll
    for (int j = 0; j < 4; ++j) acc[i][j] = (v4i){0, 0, 0, 0};

#pragma unroll 1
  for (int tap = 0; tap < 9; ++tap) {
    const int dh = tap / 3, dw = tap - dh * 3;       // uniform scalar math
    const int boff = (dh * 30 + dw) * CBYTES;        // tap shift in slab
    const int woff = tap * 256;
#pragma unroll
    for (int kc = 0; kc < 4; ++kc) {
      v4i a[4], bf[4];
#pragma unroll
      for (int mi = 0; mi < 4; ++mi)
        a[mi] = *(const v4i*)(w8t + wva[mi] + woff + kc * 64);
#pragma unroll
      for (int nt = 0; nt < 4; ++nt)
        bf[nt] = *(const v4i*)(At + av[nt] + boff + kc * 64);
#pragma unroll
      for (int mi = 0; mi < 4; ++mi)
#pragma unroll
        for (int nt = 0; nt < 4; ++nt)
          acc[mi][nt] = __builtin_amdgcn_mfma_i32_16x16x64_i8(
              a[mi], bf[nt], acc[mi][nt], 0, 0, 0);
    }
  }

  // Epilogue: D col = n15 = px, row = q*4+reg = o-within-tile.
#pragma unroll
  for (int mi = 0; mi < 4; ++mi) {
#pragma unroll
    for (int reg = 0; reg < 4; ++reg) {
      int o = ob + mi * 16 + q * 4 + reg;
      float al = alpha[o];
      size_t obase = ((size_t)b * OO + o) * HWP;
#pragma unroll
      for (int nt = 0; nt < 4; ++nt) {
        int p = p0 + nt * 16 + n15;
        if (p < HWP) out[obase + p] = al * (float)acc[mi][nt][reg];
      }
    }
  }
}

// ===========================================================================
// ==================== FALLBACK (R7 verified popcount path) =================
// ===========================================================================

__global__ __launch_bounds__(256) void pack_x_kernel(
    const float* __restrict__ x, uint32* __restrict__ apack) {
  int p = blockIdx.x * 256 + threadIdx.x;
  int j = blockIdx.y;
  int b = blockIdx.z;
  if (p >= HWP) return;
  const float* xp = x + ((size_t)(b * CC + j * 32) * HWP) + p;
  uint32 m = 0;
#pragma unroll
  for (int cc = 0; cc < 32; ++cc) {
    float v = xp[(size_t)cc * HWP];
    m |= ((uint32)(v > 0.0f)) << cc;
  }
  apack[((size_t)b * HWP + p) * 8 + j] = m;
}

__global__ __launch_bounds__(256) void pack_w_kernel(
    const float* __restrict__ M, const float* __restrict__ Z,
    const float* __restrict__ rv, uint32* __restrict__ wpack) {
  __shared__ float sacc[576];
  const int o = blockIdx.x;
  const int jh = blockIdx.y;
  const int tid = threadIdx.x;
  const size_t base = (size_t)o * 2304 + (size_t)jh * 576;
  float r[8];
#pragma unroll
  for (int k = 0; k < 8; ++k) r[k] = rv[k];
#pragma unroll
  for (int ii = 0; ii < 3; ++ii) {
    int i = tid + ii * 256;
    if (i < 576) {
      float s = M[base + i];
#pragma unroll
      for (int k = 0; k < 8; ++k) s += r[k] * Z[(size_t)k * NWT + base + i];
      sacc[i] = s;
    }
  }
  __syncthreads();
  if (tid < 18) {
    int tap = tid % 9;
    int jj = tid / 9;
    uint32 m = 0;
#pragma unroll
    for (int cc = 0; cc < 32; ++cc) {
      float v = sacc[(jj * 32 + cc) * 9 + tap];
      m |= ((uint32)(v > 0.0f)) << cc;
    }
    wpack[(o * 9 + tap) * 8 + jh * 2 + jj] = m;
  }
}

__global__ __launch_bounds__(256) void ptab_kernel(
    const uint32* __restrict__ wpack, const float* __restrict__ alpha,
    float* __restrict__ ptabA, uint32* __restrict__ ptabP) {
  int o = threadIdx.x;
  const uint32* wt = wpack + (size_t)o * 72;
  int pt[9];
#pragma unroll
  for (int t = 0; t < 9; ++t) {
    int s = 0;
#pragma unroll
    for (int j = 0; j < 8; ++j) s += __popc(wt[t * 8 + j]);
    pt[t] = s;
  }
  int row0 = pt[0] + pt[1] + pt[2], row2 = pt[6] + pt[7] + pt[8];
  int col0 = pt[0] + pt[3] + pt[6], col2 = pt[2] + pt[5] + pt[8];
  float a = alpha[o];
  const int nv[9] = {4, 6, 4, 6, 9, 6, 4, 6, 4};
  int S[9];
  S[0] = row0 + col0 - pt[0]; S[1] = row0; S[2] = row0 + col2 - pt[2];
  S[3] = col0;                S[4] = 0;    S[5] = col2;
  S[6] = row2 + col0 - pt[6]; S[7] = row2; S[8] = row2 + col2 - pt[8];
#pragma unroll
  for (int c = 0; c < 9; ++c)
    ptabA[o * 9 + c] = a * (float)(256 * nv[c] + 2 * S[c]);
  ptabP[o * 4 + 0] = __float_as_uint(-2.0f * a);
  ptabP[o * 4 + 1] = (uint32)col0;
  ptabP[o * 4 + 2] = (uint32)col2;
  ptabP[o * 4 + 3] = 0;
}

#define BCNT_ACC(T, x) asm("v_bcnt_u32_b32 %0, %1, %0" : "+v"(T) : "v"(x))

__global__ __launch_bounds__(256, 8) void conv_kernel(
    const uint32* __restrict__ apack, const uint32* __restrict__ wpack,
    const float* __restrict__ ptabA, const uint32* __restrict__ ptabP,
    float* __restrict__ out) {
  __shared__ float atab[16 * 9];
  const int rg = blockIdx.x;
  const int og = blockIdx.y;
  const int b  = blockIdx.z;
  const int tid = threadIdx.x;
  const int lane = tid & 63;
  const int wv = tid >> 6;
  const int w = lane & 31;
  const int rb = rg * 16 + wv * 4 + (lane >> 5) * 2;
  const bool wact = w < WW;

  if (tid < 144) atab[tid] = ptabA[og * 144 + tid];
  __syncthreads();

  const int wcl = wact ? w : (WW - 1);
  uint4 A[4][2];
#pragma unroll
  for (int i = 0; i < 4; ++i) {
    int rr = rb - 1 + i;
    bool v = (rr >= 0) && (rr < HH);
    const uint4* src =
        (const uint4*)(apack + ((size_t)(b * HWP + (v ? rr : 0) * WW + wcl)) * 8);
    uint4 lo = src[0], hi = src[1];
    if (!v) { lo = make_uint4(0, 0, 0, 0); hi = make_uint4(0, 0, 0, 0); }
    A[i][0] = lo;
    A[i][1] = hi;
  }

  const int wc = (w == 0) ? 0 : (w == WW - 1 ? 2 : 1);
  const int r1v = rb + 1;
  const int hc0 = (rb == 0) ? 0 : (rb == HH - 1 ? 2 : 1);
  const int hc1 = (r1v == 0) ? 0 : (r1v == HH - 1 ? 2 : 1);
  const int cls0 = hc0 * 3 + wc;
  const int cls1 = hc1 * 3 + wc;

  const size_t obase = ((size_t)b * OO + og * 16) * HWP + (size_t)rb * WW + w;
  const bool st0 = wact && (rb < HH);
  const bool st1 = wact && (r1v < HH);

  for (int oi = 0; oi < 16; ++oi) {
    const int o = og * 16 + oi;
    const int wo = __builtin_amdgcn_readfirstlane(o * 72);
    const uint32* wt = wpack + wo;
    const uint4 pm = ((const uint4*)ptabP)[o];
    const float m = __uint_as_float(pm.x);

    uint32 T00 = 0, T01 = 0, T02 = 0, T10 = 0, T11 = 0, T12 = 0;
#pragma unroll
    for (int dh = 0; dh < 3; ++dh) {
      const uint32* a0 = (const uint32*)&A[dh][0];
      const uint32* a1 = (const uint32*)&A[dh + 1][0];
#pragma unroll
      for (int j = 0; j < 8; ++j) {
        const uint32 w0 = wt[(dh * 3 + 0) * 8 + j];
        const uint32 w1 = wt[(dh * 3 + 1) * 8 + j];
        const uint32 w2 = wt[(dh * 3 + 2) * 8 + j];
        const uint32 av0 = a0[j], av1 = a1[j];
        BCNT_ACC(T00, av0 ^ w0);
        BCNT_ACC(T01, av0 ^ w1);
        BCNT_ACC(T02, av0 ^ w2);
        BCNT_ACC(T10, av1 ^ w0);
        BCNT_ACC(T11, av1 ^ w1);
        BCNT_ACC(T12, av1 ^ w2);
      }
    }
    uint32 pl = __shfl_up(T00 | (T10 << 16), 1);
    uint32 pr = __shfl_down(T02 | (T12 << 16), 1);
    if (w == 0)      pl = pm.y * 0x10001u;
    if (w == WW - 1) pr = pm.z * 0x10001u;
    uint32 tp = pl + (T01 | (T11 << 16)) + pr;
    float r0 = fmaf(m, (float)(tp & 0xffffu), atab[oi * 9 + cls0]);
    float r1 = fmaf(m, (float)(tp >> 16), atab[oi * 9 + cls1]);
    if (st0) out[obase + (size_t)oi * HWP] = r0;
    if (st1) out[obase + (size_t)oi * HWP + WW] = r1;
  }
}

// ---------------------------------------------------------------------------
extern "C" void kernel_launch(void* const* d_in, const int* in_sizes, int n_in,
                              void* d_out, int out_size, void* d_ws,
                              size_t ws_size, hipStream_t stream) {
  const float* x     = (const float*)d_in[0];  // (64,256,28,28)
  const float* M     = (const float*)d_in[1];  // (256,256,3,3)
  const float* Z     = (const float*)d_in[2];  // (8,256,256,3,3)
  const float* alpha = (const float*)d_in[3];  // (256,1,1)
  const float* rv    = (const float*)d_in[4];  // (1,8)
  float* out = (float*)d_out;                  // (64,256,28,28)

  if (ws_size >= 13434880) {
    // MFMA i8 path: a8 12,845,056 B + w8t 589,824 B.
    char* a8  = (char*)d_ws;
    char* w8t = (char*)d_ws + 12845056;
    pack_a8_kernel<<<dim3(14, BB), 256, 0, stream>>>(x, a8);
    pack_w8_kernel<<<dim3(256, 4), 256, 0, stream>>>(M, Z, rv, w8t);
    conv_mfma<<<dim3(13, BB), 256, 0, stream>>>(a8, w8t, alpha, out);
  } else {
    // Fallback: verified R7 popcount path.
    uint32* apack = (uint32*)d_ws;                         // 1,605,632 B
    uint32* wpack = (uint32*)((char*)d_ws + 1605632);      // 73,728 B
    float*  ptabA = (float*)((char*)d_ws + 1679360);       // 9,216 B
    uint32* ptabP = (uint32*)((char*)d_ws + 1688576);      // 4,096 B
    pack_x_kernel<<<dim3(4, 8, BB), 256, 0, stream>>>(x, apack);
    pack_w_kernel<<<dim3(256, 4), 256, 0, stream>>>(M, Z, rv, wpack);
    ptab_kernel<<<dim3(1), 256, 0, stream>>>(wpack, alpha, ptabA, ptabP);
    conv_kernel<<<dim3(2, 16, BB), 256, 0, stream>>>(apack, wpack, ptabA,
                                                     ptabP, out);
  }
}